// Round 15
// baseline (5486.762 us; speedup 1.0000x reference)
//
#include <hip/hip_runtime.h>
#include <cstddef>

#define HID   512
#define G4    2048   // 4*HID
#define NB    32     // batch
#define SEQL  1024
#define INPD  512
#define NBLK  128    // persistent blocks: block j owns hidden units [4j, 4j+4)

typedef _Float16 half8 __attribute__((ext_vector_type(8)));
typedef float    f32x4 __attribute__((ext_vector_type(4)));

__device__ __forceinline__ float sigm(float x) {
    return 1.0f / (1.0f + __expf(-x));
}
__device__ __forceinline__ float tanh_fast(float x) {
    float e = __expf(-2.0f * fabsf(x));
    float t = (1.0f - e) / (1.0f + e);
    return copysignf(t, x);
}

// p-major permuted gate index: g'' = j*16 + p, p = uu*4 + ty
// (uu = unit within block 0..3, ty = gate type). orig row = ty*HID + j*4 + uu.
__device__ __forceinline__ int orig_gate(int gp) {
    int p = gp & 15, j = gp >> 4;
    return (p & 3) * HID + j * 4 + (p >> 2);
}

// ---- one-time: W_hh fp32 [2048][512] -> fp16, wh[j][p][k], p = uu*4 + ty
__global__ __launch_bounds__(256) void conv_whh(const float* __restrict__ whh,
                                                _Float16* __restrict__ wh) {
    int e = blockIdx.x * 256 + threadIdx.x;   // e < 2048*512
    int R = e >> 9, k = e & 511;
    int ty = R >> 9, rem = R & 511;
    int j = rem >> 2, uu = rem & 3;
    int p = uu * 4 + ty;
    wh[((size_t)j * 16 + p) * 512 + k] = (_Float16)whh[e];
}

// ---- one-time: h0 fp32 -> fp16 into hbuf buffer 0
__global__ __launch_bounds__(256) void conv_h0(const float* __restrict__ h0,
                                               _Float16* __restrict__ hb) {
    int e = blockIdx.x * 256 + threadIdx.x;   // e < NB*HID
    hb[e] = (_Float16)h0[e];
}

// x_proj chunk GEMM with p-major PERMUTED output columns (unchanged)
__global__ __launch_bounds__(256) void xproj_gemm(const float* __restrict__ x,
                                                  const float* __restrict__ wih,
                                                  const float* __restrict__ bih,
                                                  const float* __restrict__ bhh,
                                                  float* __restrict__ xbuf,
                                                  int chunk, int SC) {
    __shared__ float As[16][68];
    __shared__ float Bs[16][68];
    const int m0 = blockIdx.x * 64;
    const int n0 = blockIdx.y * 64;
    const int tid = threadIdx.x;
    const int tx = tid % 16;
    const int ty = tid / 16;
    const int lr  = tid / 4;
    const int lc4 = tid % 4;

    float acc[4][4] = {};

    const int m = m0 + lr;
    const int b  = m / SC;
    const int tl = m % SC;
    const float* arow_base = x + ((size_t)b * SEQL + (size_t)chunk * SC + tl) * INPD + lc4 * 4;
    const float* brow_base = wih + (size_t)orig_gate(n0 + lr) * INPD + lc4 * 4;

    for (int k0 = 0; k0 < 512; k0 += 16) {
        float4 a4 = *(const float4*)(arow_base + k0);
        float4 b4 = *(const float4*)(brow_base + k0);
        As[lc4 * 4 + 0][lr] = a4.x;
        As[lc4 * 4 + 1][lr] = a4.y;
        As[lc4 * 4 + 2][lr] = a4.z;
        As[lc4 * 4 + 3][lr] = a4.w;
        Bs[lc4 * 4 + 0][lr] = b4.x;
        Bs[lc4 * 4 + 1][lr] = b4.y;
        Bs[lc4 * 4 + 2][lr] = b4.z;
        Bs[lc4 * 4 + 3][lr] = b4.w;
        __syncthreads();
        #pragma unroll
        for (int kk = 0; kk < 16; ++kk) {
            float4 av = *(const float4*)&As[kk][ty * 4];
            float4 bv = *(const float4*)&Bs[kk][tx * 4];
            float a[4] = {av.x, av.y, av.z, av.w};
            float bb[4] = {bv.x, bv.y, bv.z, bv.w};
            #pragma unroll
            for (int i = 0; i < 4; ++i)
                #pragma unroll
                for (int jj = 0; jj < 4; ++jj)
                    acc[i][jj] = fmaf(a[i], bb[jj], acc[i][jj]);
        }
        __syncthreads();
    }

    #pragma unroll
    for (int i = 0; i < 4; ++i) {
        int mo = m0 + ty * 4 + i;
        float* orow = xbuf + (size_t)mo * G4;
        #pragma unroll
        for (int jj = 0; jj < 4; ++jj) {
            int n = n0 + tx * 4 + jj;
            int og = orig_gate(n);
            orow[n] = acc[i][jj] + bih[og] + bhh[og];
        }
    }
}

// Persistent recurrence: 2-wave blocks, full-K MFMA, no partial reduce.
// 128 blocks x 128 threads; block j owns units [4j,4j+4) = 16 gates (p-major).
// Wave mt computes C[16 batches][16 gates] over full K=512:
//   B-frag: 16 x half8 in VGPRs (whole W slice for this wave), loaded once.
//   A-frag: 32 u64 direct from hbuf (LLC) per step -> 16 MFMA (2 acc chains).
//   D: lane l holds C[b=16mt+(l>>4)*4+r][p=l&15], r=0..3.
// Transpose via 544-float LDS: lane writes f32x4 at [(mt*4+(l>>4))*68+(l&15)*4],
// cell-lane (uu=l&3, b=16mt+4*(l>>4)+((l>>2)&3)) reads 4 types at
// [(mt*4+(l>>4))*68+(4*uu+ty)*4+((l>>2)&3)] -- 2-way banks both sides.
// Cell: 1 unit/thread (128 = 32b x 4u), publish one 2B fp16 store (LLC).
// 3 cheap 2-wave barriers/step: poll-release, transpose, drain.
__global__ __launch_bounds__(128, 1)
void lstm_persist(const _Float16* __restrict__ wh,   // [NBLK][16][512] fp16
                  const float* __restrict__ xbuf,    // [NB*SC][G4] p-major perm
                  const float* __restrict__ c0,
                  unsigned long long* __restrict__ hbuf, // fp16 [2][NB][HID] as u64
                  float* __restrict__ cstate,        // [NB][HID]
                  float* __restrict__ out,           // [NB][SEQL][HID]
                  int* __restrict__ flags,           // [NBLK*32]
                  int step_base, int SC) {
    __shared__ __align__(16) float tr[2 * 4 * 68];   // [wave*4+grp][p*4+r], stride 68

    const int j  = blockIdx.x;
    const int t  = threadIdx.x;
    const int u0 = 4 * j;

    const int mt   = t >> 6, lane = t & 63;
    const int arow = 16 * mt + (lane & 15);   // A row (batch)
    const int p_b  = lane & 15;               // B row (gate p)
    const int koff = (lane >> 4) * 2;         // u64 offset within 32-half group

    // cell role: unit uu = lane&3, batch b_c = 16mt + 4*(lane>>4) + ((lane>>2)&3)
    const int uu  = lane & 3;
    const int b_c = 16 * mt + 4 * (lane >> 4) + ((lane >> 2) & 3);
    const int grp = lane >> 4, rr = (lane >> 2) & 3;

    // ---- B fragments: full K in 64 VGPRs, loaded once
    half8 wf[16];
    {
        const _Float16* wrow = wh + ((size_t)j * 16 + p_b) * 512 + (lane >> 4) * 8;
        #pragma unroll
        for (int q = 0; q < 16; ++q)
            wf[q] = *(const half8*)(wrow + q * 32);
    }

    // ---- cell state: 1 unit/thread
    float c = (step_base == 0 ? c0 : cstate)[b_c * HID + u0 + uu];

    for (int s = 0; s < SC; ++s) {
        const int g = step_base + s;

        // ---- xg prefetch: the 4 gate types of this unit = one float4
        float4 xg = *(const float4*)(xbuf + ((size_t)b_c * SC + s) * G4 + 16 * j + 4 * uu);

        // ---- poll: each of the 128 threads spins on its own flag line
        while (__hip_atomic_load(&flags[t * 32], __ATOMIC_RELAXED,
                                 __HIP_MEMORY_SCOPE_AGENT) < g)
            __builtin_amdgcn_s_sleep(1);
        __syncthreads();

        // ---- A fragments direct from hbuf (LLC): 32 u64, one latency
        const unsigned long long* hs8 = hbuf + (size_t)(g & 1) * 4096
                                      + (size_t)arow * 128 + koff;
        half8 av[16];
        #pragma unroll
        for (int q = 0; q < 16; ++q) {
            unsigned long long va = __hip_atomic_load(hs8 + q * 8,     __ATOMIC_RELAXED,
                                                      __HIP_MEMORY_SCOPE_AGENT);
            unsigned long long vb = __hip_atomic_load(hs8 + q * 8 + 1, __ATOMIC_RELAXED,
                                                      __HIP_MEMORY_SCOPE_AGENT);
            __builtin_memcpy(&av[q], &va, 8);
            __builtin_memcpy((char*)&av[q] + 8, &vb, 8);
        }

        // ---- 16 MFMA, 2 interleaved acc chains
        f32x4 aA = {0.f, 0.f, 0.f, 0.f}, aB = {0.f, 0.f, 0.f, 0.f};
        #pragma unroll
        for (int q = 0; q < 16; q += 2) {
            aA = __builtin_amdgcn_mfma_f32_16x16x32_f16(av[q],     wf[q],     aA, 0, 0, 0);
            aB = __builtin_amdgcn_mfma_f32_16x16x32_f16(av[q + 1], wf[q + 1], aB, 0, 0, 0);
        }
        f32x4 acc = aA + aB;

        // ---- transpose through LDS (b128 write; barrier; 4 scalar reads)
        *(f32x4*)&tr[(mt * 4 + (lane >> 4)) * 68 + (lane & 15) * 4] = acc;
        __syncthreads();

        float v0 = tr[(mt * 4 + grp) * 68 + (4 * uu + 0) * 4 + rr];
        float v1 = tr[(mt * 4 + grp) * 68 + (4 * uu + 1) * 4 + rr];
        float v2 = tr[(mt * 4 + grp) * 68 + (4 * uu + 2) * 4 + rr];
        float v3 = tr[(mt * 4 + grp) * 68 + (4 * uu + 3) * 4 + rr];

        // ---- cell update (p-major: ty 0..3 = i,f,g,o)
        float gi = v0 + xg.x, gf = v1 + xg.y, gg = v2 + xg.z, go = v3 + xg.w;
        c = fmaf(sigm(gf), c, sigm(gi) * tanh_fast(gg));
        float h = sigm(go) * tanh_fast(c);

        // ---- publish fp16 (2B relaxed agent store, quad-merged across uu)
        _Float16 hh = (_Float16)h;
        unsigned short hu;
        __builtin_memcpy(&hu, &hh, 2);
        __hip_atomic_store((unsigned short*)hbuf + (size_t)((g + 1) & 1) * 16384
                               + b_c * 512 + u0 + uu,
                           hu, __ATOMIC_RELAXED, __HIP_MEMORY_SCOPE_AGENT);
        __syncthreads();   // drain: publish acked at LLC (vmcnt(0) before barrier)

        // ---- arrive
        if (t == 0)
            __hip_atomic_store(&flags[j * 32], g + 1,
                               __ATOMIC_RELAXED, __HIP_MEMORY_SCOPE_AGENT);

        // ---- out store (fp32) AFTER arrive: HBM ack overlaps next poll
        out[((size_t)b_c * SEQL + g) * HID + u0 + uu] = h;
    }

    cstate[b_c * HID + u0 + uu] = c;
}

__global__ __launch_bounds__(256) void finalize(const _Float16* __restrict__ hfin,
                                                const float* __restrict__ cs,
                                                float* __restrict__ out) {
    int i = blockIdx.x * blockDim.x + threadIdx.x;
    size_t base = (size_t)NB * SEQL * HID;
    if (i < NB * HID) {
        out[base + i] = (float)hfin[i];
        out[base + NB * HID + i] = cs[i];
    }
}

extern "C" void kernel_launch(void* const* d_in, const int* in_sizes, int n_in,
                              void* d_out, int out_size, void* d_ws, size_t ws_size,
                              hipStream_t stream) {
    const float* x   = (const float*)d_in[0];
    const float* h0  = (const float*)d_in[1];
    const float* c0  = (const float*)d_in[2];
    const float* wih = (const float*)d_in[3];
    const float* whh = (const float*)d_in[4];
    const float* bih = (const float*)d_in[5];
    const float* bhh = (const float*)d_in[6];
    float* out = (float*)d_out;

    char* ws = (char*)d_ws;
    int*       flags  = (int*)ws;                                  // 16 KB
    _Float16*  hbuf_h = (_Float16*)(ws + 16384);                   // 64 KB (2 bufs)
    float*     cstate = (float*)(ws + 16384 + 65536);              // 64 KB
    _Float16*  wh_h   = (_Float16*)(ws + 16384 + 65536 + 65536);   // 2 MB
    float*     xbuf   = (float*)(ws + 16384 + 65536 + 65536 + 2097152);

    size_t fixed = 16384 + 65536 + 65536 + 2097152;
    int SC = SEQL;
    while (SC > 64 && fixed + (size_t)NB * SC * G4 * sizeof(float) > ws_size) SC >>= 1;

    hipMemsetAsync(flags, 0, 16384, stream);
    conv_whh<<<(2048 * 512) / 256, 256, 0, stream>>>(whh, wh_h);
    conv_h0<<<(NB * HID) / 256, 256, 0, stream>>>(h0, hbuf_h);

    int nchunks = SEQL / SC;
    for (int ch = 0; ch < nchunks; ++ch) {
        dim3 grd(NB * SC / 64, G4 / 64);
        xproj_gemm<<<grd, 256, 0, stream>>>(x, wih, bih, bhh, xbuf, ch, SC);
        lstm_persist<<<NBLK, 128, 0, stream>>>(wh_h, xbuf, c0,
                                               (unsigned long long*)hbuf_h,
                                               cstate, out, flags, ch * SC, SC);
    }

    // total steps = 1024 (even) -> final h parity is buffer 0
    finalize<<<(NB * HID + 255) / 256, 256, 0, stream>>>(hbuf_h, cstate, out);
}